// Round 2
// baseline (827.455 us; speedup 1.0000x reference)
//
#include <hip/hip_runtime.h>

#define BATCH  262144
#define N_FEAT 256
#define N_INT  255
#define N_LEAF 256
#define ROWS   16
#define THREADS 256
#define NSUB   16   // subtrees rooted at depth 4

// Fully-unrolled DFS over one depth-4-rooted subtree (local depths J=0..3 <->
// global depths 4..7). prefix is compile-time-propagated per inlined call
// site, so all LDS offsets fold to ds_read immediates off a runtime base.
template<int J>
__device__ __forceinline__ float dfs(const float* __restrict__ row,
                                     int s, int prefix, float p,
                                     const float* __restrict__ leaf) {
  if constexpr (J == 4) {
    return p * leaf[(s << 4) + prefix];          // leaf index b0..b7 = (s<<4)|prefix
  } else {
    int node = ((1 << (J + 4)) - 1) + (s << J) + prefix;  // heap index, depth J+4
    float w = row[node];
    return dfs<J + 1>(row, s, (prefix << 1),     p * (1.0f - w), leaf)
         + dfs<J + 1>(row, s, (prefix << 1) | 1, p * w,          leaf);
  }
}

__global__ __launch_bounds__(THREADS, 8) void sdt_kernel(
    const float* __restrict__ x,
    const float* __restrict__ split_cond,
    const float* __restrict__ u,
    const float* __restrict__ leaf_values,
    const int* __restrict__ split_idx,
    float* __restrict__ out)
{
  // 16 rows x 257 (pad +1: phase-2 reads are bank (r + node) % 32 -> at most
  // 2 lanes/bank in a wave = free). ~18.5 KB total -> 8 blocks/CU, 32 waves/CU.
  __shared__ float s_w[ROWS][N_FEAT + 1];   // 16.4 KB
  __shared__ float s_leaf[N_LEAF];          //  1.0 KB
  __shared__ float s_acc[NSUB][ROWS];       //  1.0 KB

  const int tid  = threadIdx.x;
  const int row0 = blockIdx.x * ROWS;

  s_leaf[tid] = leaf_values[tid];

  // ---- Phase 1: thread = node, loop over the tile's 16 rows. ----
  // u loads: lanes cover contiguous float2s -> 512 B/wave coalesced.
  // x gather: whole block shares one 1KB x row per iter -> L1-resident.
  // cond/idx: read once per thread -> registers, no LDS round-trip.
  if (tid < N_INT) {
    const float sc = split_cond[tid];
    const int   si = split_idx[tid];
    const float2* up = (const float2*)(u + (size_t)row0 * (2 * N_INT)) + tid;
    const float*  xp = x + (size_t)row0 * N_FEAT + si;
    #pragma unroll 8
    for (int r = 0; r < ROWS; ++r) {
      float2 uv = up[(size_t)r * N_INT];
      float  xv = xp[(size_t)r * N_FEAT];
      float u0 = fminf(fmaxf(uv.x, 1e-10f), 1.0f);
      float u1 = fminf(fmaxf(uv.y, 1e-10f), 1.0f);
      float g0 = -__logf(-__logf(u0));          // Gumbel(0,1)
      float g1 = -__logf(-__logf(u1));
      float z  = (xv - sc) + (g0 - g1);
      float w  = 1.0f / (1.0f + __expf(-z));    // sigmoid
      s_w[r][tid] = w;
    }
  }
  __syncthreads();

  // ---- Phase 2: thread = (subtree s in 0..15, row r in 0..15). ----
  // Path factors for depths 0..3, then DFS over the depth-4 subtree.
  {
    const int s = tid >> 4;
    const int r = tid & 15;
    const float* row = &s_w[r][0];
    float w0 = row[0];                  // depth 0, bit b0 = (s>>3)&1
    float f0 = (s & 8) ? w0 : (1.0f - w0);
    float w1 = row[1 + (s >> 3)];       // depth 1, bit b1 = (s>>2)&1
    float f1 = (s & 4) ? w1 : (1.0f - w1);
    float w2 = row[3 + (s >> 2)];       // depth 2, bit b2 = (s>>1)&1
    float f2 = (s & 2) ? w2 : (1.0f - w2);
    float w3 = row[7 + (s >> 1)];       // depth 3, bit b3 = s&1
    float f3 = (s & 1) ? w3 : (1.0f - w3);
    s_acc[s][r] = dfs<0>(row, s, 0, (f0 * f1) * (f2 * f3), s_leaf);
  }
  __syncthreads();

  if (tid < ROWS) {
    float v = 0.0f;
    #pragma unroll
    for (int s = 0; s < NSUB; ++s) v += s_acc[s][tid];
    out[row0 + tid] = v;
  }
}

extern "C" void kernel_launch(void* const* d_in, const int* in_sizes, int n_in,
                              void* d_out, int out_size, void* d_ws, size_t ws_size,
                              hipStream_t stream) {
  const float* x           = (const float*)d_in[0];
  const float* split_cond  = (const float*)d_in[1];
  const float* u           = (const float*)d_in[2];
  const float* leaf_values = (const float*)d_in[3];
  const int*   split_idx   = (const int*)d_in[4];
  float*       out         = (float*)d_out;

  sdt_kernel<<<dim3(BATCH / ROWS), dim3(THREADS), 0, stream>>>(
      x, split_cond, u, leaf_values, split_idx, out);
}